// Round 12
// baseline (162.653 us; speedup 1.0000x reference)
//
#include <hip/hip_runtime.h>

typedef unsigned short u16;
typedef unsigned int u32;
typedef __bf16 bf16x8 __attribute__((ext_vector_type(8)));
typedef u16 u16x8 __attribute__((ext_vector_type(8)));
typedef float f32x4 __attribute__((ext_vector_type(4)));

__device__ __forceinline__ u16 f2bf(float f) {
  u32 u = __float_as_uint(f);
  u32 r = (u + 0x7FFFu + ((u >> 16) & 1u)) >> 16;  // RNE
  return (u16)r;
}

// -------- kernel 0: cast x fp32 -> bf16 A[4608][512]  (+ wpack + out-zero) --
__global__ void k_cast(const float* __restrict__ x, u16* __restrict__ A,
                       const float* __restrict__ w2, const float* __restrict__ w3,
                       u16* __restrict__ p2, u16* __restrict__ p3,
                       float* __restrict__ out) {
  int t = blockIdx.x * 256 + threadIdx.x;
  const float4* xp = (const float4*)x + (size_t)t * 2;
  float4 v0 = xp[0], v1 = xp[1];
  u16x8 r;
  r[0] = f2bf(v0.x); r[1] = f2bf(v0.y); r[2] = f2bf(v0.z); r[3] = f2bf(v0.w);
  r[4] = f2bf(v1.x); r[5] = f2bf(v1.y); r[6] = f2bf(v1.z); r[7] = f2bf(v1.w);
  *(u16x8*)(A + (size_t)t * 8) = r;
  if (blockIdx.x == 0 && threadIdx.x < 65) out[threadIdx.x] = 0.f;
  if (t < 18432) {
    int tt = t >> 11, oc = (t >> 5) & 63, ic = t & 31;
    p2[t] = f2bf(w2[(oc * 32 + ic) * 9 + tt]);
  }
  if (t < 73728) {
    int tt = t >> 13, oc = (t >> 6) & 127, ic = t & 63;
    p3[t] = f2bf(w3[(oc * 64 + ic) * 9 + tt]);
  }
}

// ------- kernel 1: symmetric C = A*A^T with fused max over col/row 9-groups -
// R11: VGPR-staged pipeline. R10's global_load_lds dbuf was defeated by
// barrier semantics (s_barrier drains vmcnt(0) incl. the other-buffer DMA ->
// full HBM latency exposed each iter; MfmaUtil 9.4%). Now: per iter, issue
// next tile's 8 global_load_dwordx4 into regs (no wait), compute current
// from LDS, THEN ds_write regs -> idle buffer (compiler places the vmcnt
// wait after compute, hiding HBM latency under MFMA); barrier drains only
// cheap LDS writes. Same verified XOR-swizzle layout + epilogue (R8-R10).
__global__ __launch_bounds__(256) void k_gemm_smax(const u16* __restrict__ A,
                                                   float* __restrict__ Smax,
                                                   float* __restrict__ Sx) {
  __shared__ char smem[65536];   // 2 x (As 16KB + Bs 16KB); epilogue slab reuses
  float* slab = (float*)smem;    // 64 x 129 f32 = 33024 B, used after K-loop
  const int tlin = blockIdx.x;
  int rb = (int)((73.0f - sqrtf((float)(5329 - 8 * tlin))) * 0.5f);
  while (rb * 36 - rb * (rb - 1) / 2 > tlin) --rb;                  // safety
  while ((rb + 1) * 36 - (rb + 1) * rb / 2 <= tlin) ++rb;           // safety
  const int cb = rb + (tlin - (rb * 36 - rb * (rb - 1) / 2));
  const int rowBase = rb * 128, colBase = cb * 128;
  const int tid = threadIdx.x, wave = tid >> 6, lane = tid & 63;
  const int lrow = lane & 15, lk = lane >> 4;  // mfma fragment map
  const int xr = lrow & 7;
  const int wr = (wave & 1) * 64, wc = (wave >> 1) * 64;
  // staging map: load L covers row sr+L*32, chunk sp (8 x 16B per 128B row)
  const int sr = tid >> 3, sp = tid & 7;

  f32x4 acc[4][4];
#pragma unroll
  for (int rt = 0; rt < 4; ++rt)
#pragma unroll
    for (int ct = 0; ct < 4; ++ct) { f32x4 z = {0.f, 0.f, 0.f, 0.f}; acc[rt][ct] = z; }

  u16x8 ra[4], rbv[4];
  const u16* Ab = A + (size_t)(rowBase + sr) * 512 + sp * 8;
  const u16* Bb = A + (size_t)(colBase + sr) * 512 + sp * 8;

#pragma unroll
  for (int L = 0; L < 4; ++L) {
    ra[L] = *(const u16x8*)(Ab + (size_t)L * 32 * 512);
    rbv[L] = *(const u16x8*)(Bb + (size_t)L * 32 * 512);
  }
  {
    u16* As = (u16*)smem;
    u16* Bs = (u16*)(smem + 16384);
    const int wp = (sp ^ (sr & 7)) * 8;
#pragma unroll
    for (int L = 0; L < 4; ++L) {
      *(u16x8*)(As + (L * 32 + sr) * 64 + wp) = ra[L];
      *(u16x8*)(Bs + (L * 32 + sr) * 64 + wp) = rbv[L];
    }
  }
  __syncthreads();

  for (int k = 0; k < 8; ++k) {
    if (k < 7) {  // issue next tile's loads; no wait here
      int k0 = (k + 1) * 64;
#pragma unroll
      for (int L = 0; L < 4; ++L) {
        ra[L] = *(const u16x8*)(Ab + (size_t)L * 32 * 512 + k0);
        rbv[L] = *(const u16x8*)(Bb + (size_t)L * 32 * 512 + k0);
      }
    }
    {
      char* base = smem + ((k & 1) << 15);
      u16* As = (u16*)base;
      u16* Bs = (u16*)(base + 16384);
#pragma unroll
      for (int s = 0; s < 2; ++s) {
        bf16x8 af[4], bf[4];
#pragma unroll
        for (int rt = 0; rt < 4; ++rt)
          af[rt] = *(const bf16x8*)(As + (wr + rt * 16 + lrow) * 64 +
                                    ((u32)(s * 4 + lk) ^ xr) * 8);
#pragma unroll
        for (int ct = 0; ct < 4; ++ct)
          bf[ct] = *(const bf16x8*)(Bs + (wc + ct * 16 + lrow) * 64 +
                                    ((u32)(s * 4 + lk) ^ xr) * 8);
#pragma unroll
        for (int rt = 0; rt < 4; ++rt)
#pragma unroll
          for (int ct = 0; ct < 4; ++ct)
            acc[rt][ct] = __builtin_amdgcn_mfma_f32_16x16x32_bf16(af[rt], bf[ct],
                                                                  acc[rt][ct], 0, 0, 0);
      }
    }
    if (k < 7) {  // vmcnt wait lands here, after ~500 cyc of MFMA
      char* base = smem + (((k + 1) & 1) << 15);
      u16* As = (u16*)base;
      u16* Bs = (u16*)(base + 16384);
      const int wp = (sp ^ (sr & 7)) * 8;
#pragma unroll
      for (int L = 0; L < 4; ++L) {
        *(u16x8*)(As + (L * 32 + sr) * 64 + wp) = ra[L];
        *(u16x8*)(Bs + (L * 32 + sr) * 64 + wp) = rbv[L];
      }
      __syncthreads();
    }
  }

  // C/D layout: col=lane&15, row=(lane>>4)*4+reg [measured]. Verified R8-R10.
  const int g0c = colBase / 9, offc = colBase % 9;
  const int g0r = rowBase / 9, offr = rowBase % 9;
  const int nph = (rb == cb) ? 2 : 4;
  for (int ph = 0; ph < nph; ++ph) {
    __syncthreads();
    if (ph < 2) {
      if ((wave & 1) == ph) {
#pragma unroll
        for (int rt = 0; rt < 4; ++rt)
#pragma unroll
          for (int ct = 0; ct < 4; ++ct)
#pragma unroll
            for (int r = 0; r < 4; ++r)
              slab[(rt * 16 + lk * 4 + r) * 129 + wc + ct * 16 + lrow] = acc[rt][ct][r];
      }
    } else {
      if ((wave >> 1) == ph - 2) {
#pragma unroll
        for (int rt = 0; rt < 4; ++rt)
#pragma unroll
          for (int ct = 0; ct < 4; ++ct)
#pragma unroll
            for (int r = 0; r < 4; ++r)
              slab[(ct * 16 + lrow) * 129 + wr + rt * 16 + lk * 4 + r] = acc[rt][ct][r];
      }
    }
    __syncthreads();
    for (int it = tid; it < 1024; it += 256) {
      int line = it >> 4, s = it & 15;
      float m = -3.0e38f;
      if (ph < 2) {
        int g = g0c + s;
        int cs = 9 * g - colBase, ce = cs + 9;
        cs = cs < 0 ? 0 : cs;
        ce = ce > 128 ? 128 : ce;
        if (cs >= ce) continue;
        const float* p = slab + line * 129;
        for (int c = cs; c < ce; ++c) m = fmaxf(m, p[c]);
        int r = rowBase + ph * 64 + line;
        if (s == 0 && offc != 0) Sx[(size_t)r * 36 + (cb - 1)] = m;
        else Smax[(size_t)r * 512 + g] = m;
      } else {
        int g = g0r + s;
        int rs = 9 * g - rowBase, re = rs + 9;
        rs = rs < 0 ? 0 : rs;
        re = re > 128 ? 128 : re;
        if (rs >= re) continue;
        const float* p = slab + line * 129;
        for (int r2 = rs; r2 < re; ++r2) m = fmaxf(m, p[r2]);
        int cgl = colBase + (ph - 2) * 64 + line;
        if (s == 0 && offr != 0) Sx[(size_t)cgl * 36 + (rb - 1)] = m;
        else Smax[(size_t)cgl * 512 + g] = m;
      }
    }
  }
}

// ---------- kernel 2: mean over o (+Sx boundary combine) -> sim -------------
__global__ void k_reduce_o(const float* __restrict__ Smax, const float* __restrict__ Sx,
                           float* __restrict__ sim) {
  int idx = blockIdx.x * 256 + threadIdx.x;  // 262144
  int j = idx & 63, i = (idx >> 6) & 63, b = (idx >> 12) & 7, a = idx >> 15;
  int g = b * 64 + j;
  int t9 = 9 * g;
  int k = (t9 + 8) >> 7;                        // candidate tile boundary
  bool part = ((u32)(128 * k - t9 - 1) < 8u);   // 128k strictly inside (t9, t9+9)
  const float* p = Smax + (size_t)(a * 576 + i * 9) * 512 + g;
  const float* q = Sx + (size_t)(a * 576 + i * 9) * 36 + (k - 1);
  float s = 0.f;
#pragma unroll
  for (int o = 0; o < 9; ++o) {
    float v = p[o * 512];
    if (part) v = fmaxf(v, q[o * 36]);
    s += v;
  }
  sim[idx] = s * (1.f / 9.f);  // sim[(a*8+b)*4096 + i*64 + j]
}

// ---------- kernel 3: conv1 (1->32) + ReLU + maxpool2, channels-last bf16 ---
__global__ __launch_bounds__(256) void k_conv1pool(const float* __restrict__ sim,
                                                   const float* __restrict__ w1,
                                                   const float* __restrict__ b1,
                                                   u16* __restrict__ h1) {
  __shared__ float tin[4096];
  const int pair = blockIdx.x, ocg = blockIdx.y, tid = threadIdx.x;
  const float4* src = (const float4*)(sim + (size_t)pair * 4096);
  for (int i = tid; i < 1024; i += 256) ((float4*)tin)[i] = src[i];
  __syncthreads();
  float wv[8][9], bs[8];
#pragma unroll
  for (int o = 0; o < 8; ++o) {
#pragma unroll
    for (int q = 0; q < 9; ++q) wv[o][q] = w1[(ocg * 8 + o) * 9 + q];
    bs[o] = b1[ocg * 8 + o];
  }
  for (int pp = tid; pp < 1024; pp += 256) {
    int py = pp >> 5, px = pp & 31;
    float m[8];
#pragma unroll
    for (int o = 0; o < 8; ++o) m[o] = 0.f;
#pragma unroll
    for (int dy = 0; dy < 2; ++dy)
#pragma unroll
      for (int dx = 0; dx < 2; ++dx) {
        float s[8];
#pragma unroll
        for (int o = 0; o < 8; ++o) s[o] = bs[o];
        int yy = py * 2 + dy, xx0 = px * 2 + dx;
#pragma unroll
        for (int ky = 0; ky < 3; ++ky) {
          int y = yy + ky - 1;
          if ((unsigned)y < 64u) {
#pragma unroll
            for (int kx = 0; kx < 3; ++kx) {
              int x = xx0 + kx - 1;
              if ((unsigned)x < 64u) {
                float v = tin[y * 64 + x];
#pragma unroll
                for (int o = 0; o < 8; ++o) s[o] += wv[o][ky * 3 + kx] * v;
              }
            }
          }
        }
#pragma unroll
        for (int o = 0; o < 8; ++o) m[o] = fmaxf(m[o], fmaxf(s[o], 0.f));
      }
    u16x8 r;
#pragma unroll
    for (int o = 0; o < 8; ++o) r[o] = f2bf(m[o]);
    *(u16x8*)&h1[(((size_t)pair * 32 + py) * 32 + px) * 32 + ocg * 8] = r;
  }
}

// ---------- kernel 4: conv2 MFMA (32->64) + ReLU + maxpool2 -----------------
__global__ __launch_bounds__(256) void k_conv2pool(const u16* __restrict__ h1,
                                                   const u16* __restrict__ wp2,
                                                   const float* __restrict__ b2,
                                                   u16* __restrict__ h2) {
  __shared__ u16 tile[18 * 34 * 40];  // 48960 B
  const int pair = blockIdx.x, yh = blockIdx.y, tid = threadIdx.x;
  const int wave = tid >> 6, lane = tid & 63, l15 = lane & 15, quad = lane >> 4;
  u16x8 z8 = {0, 0, 0, 0, 0, 0, 0, 0};
  for (int i = tid; i < 3060; i += 256) ((u16x8*)tile)[i] = z8;
  __syncthreads();
  for (int f = tid; f < 1152; f += 256) {
    int i = f >> 6, rem = f & 63, px = rem >> 1, half = rem & 1;
    int gr = yh * 16 - 1 + i;
    if ((unsigned)gr < 32u)
      *(u16x8*)&tile[(i * 34 + 1 + px) * 40 + half * 16] =
          *(const u16x8*)&h1[(((size_t)pair * 32 + gr) * 32 + px) * 32 + half * 16];
  }
  __syncthreads();

  f32x4 acc[8][4];
#pragma unroll
  for (int m = 0; m < 8; ++m)
#pragma unroll
    for (int n = 0; n < 4; ++n) { f32x4 z = {0.f, 0.f, 0.f, 0.f}; acc[m][n] = z; }

  for (int t = 0; t < 9; ++t) {
    int ky = t / 3, kx = t % 3;
    bf16x8 wf[4];
#pragma unroll
    for (int nt = 0; nt < 4; ++nt)
      wf[nt] = *(const bf16x8*)&wp2[((t * 64 + nt * 16 + l15) << 5) + quad * 8];
#pragma unroll
    for (int rr = 0; rr < 4; ++rr)
#pragma unroll
      for (int xh = 0; xh < 2; ++xh) {
        int lr = wave * 4 + rr;
        bf16x8 af = *(const bf16x8*)&tile[((lr + ky) * 34 + xh * 16 + l15 + kx) * 40 +
                                          quad * 8];
#pragma unroll
        for (int nt = 0; nt < 4; ++nt)
          acc[rr * 2 + xh][nt] =
              __builtin_amdgcn_mfma_f32_16x16x32_bf16(af, wf[nt], acc[rr * 2 + xh][nt],
                                                      0, 0, 0);
      }
  }

  float bv[4];
#pragma unroll
  for (int nt = 0; nt < 4; ++nt) bv[nt] = b2[nt * 16 + l15];
#pragma unroll
  for (int rp = 0; rp < 2; ++rp)
#pragma unroll
    for (int xh = 0; xh < 2; ++xh) {
      int py = yh * 8 + wave * 2 + rp;
      int px0 = xh * 8 + quad * 2;
#pragma unroll
      for (int nt = 0; nt < 4; ++nt) {
        f32x4 va = acc[(rp * 2) * 2 + xh][nt], vb = acc[(rp * 2 + 1) * 2 + xh][nt];
        float p0 = fmaxf(fmaxf(fmaxf(va[0], va[1]), fmaxf(vb[0], vb[1])) + bv[nt], 0.f);
        float p1 = fmaxf(fmaxf(fmaxf(va[2], va[3]), fmaxf(vb[2], vb[3])) + bv[nt], 0.f);
        size_t base = (((size_t)pair * 16 + py) * 16 + px0) * 64 + nt * 16 + l15;
        h2[base] = f2bf(p0);
        h2[base + 64] = f2bf(p1);
      }
    }
}

// ---------- kernel 5: conv3 MFMA (64->128) + ReLU ---------------------------
__global__ __launch_bounds__(256) void k_conv3(const u16* __restrict__ h2,
                                               const u16* __restrict__ wp3,
                                               const float* __restrict__ b3,
                                               float* __restrict__ h3) {
  __shared__ u16 tile[18 * 18 * 72];  // 46656 B
  const int pair = blockIdx.x, oh = blockIdx.y, tid = threadIdx.x;
  const int wave = tid >> 6, lane = tid & 63, l15 = lane & 15, quad = lane >> 4;
  u16x8 z8 = {0, 0, 0, 0, 0, 0, 0, 0};
  for (int i = tid; i < 2916; i += 256) ((u16x8*)tile)[i] = z8;
  __syncthreads();
  for (int f = tid; f < 2048; f += 256) {
    int row = f >> 7, rem = f & 127, px = rem >> 3, seg = rem & 7;
    *(u16x8*)&tile[((row + 1) * 18 + px + 1) * 72 + seg * 8] =
        *(const u16x8*)&h2[(((size_t)pair * 16 + row) * 16 + px) * 64 + seg * 8];
  }
  __syncthreads();

  f32x4 acc[4][4];
#pragma unroll
  for (int m = 0; m < 4; ++m)
#pragma unroll
    for (int n = 0; n < 4; ++n) { f32x4 z = {0.f, 0.f, 0.f, 0.f}; acc[m][n] = z; }

  for (int t = 0; t < 9; ++t) {
    int ky = t / 3, kx = t % 3;
#pragma unroll
    for (int s = 0; s < 2; ++s) {
      bf16x8 wf[4];
#pragma unroll
      for (int nt = 0; nt < 4; ++nt)
        wf[nt] = *(const bf16x8*)&wp3[((t * 128 + oh * 64 + nt * 16 + l15) << 6) +
                                      s * 32 + quad * 8];
#pragma unroll
      for (int yt = 0; yt < 4; ++yt) {
        int y = wave * 4 + yt;
        bf16x8 af = *(const bf16x8*)&tile[((y + ky) * 18 + l15 + kx) * 72 + s * 32 +
                                          quad * 8];
#pragma unroll
        for (int nt = 0; nt < 4; ++nt)
          acc[yt][nt] = __builtin_amdgcn_mfma_f32_16x16x32_bf16(af, wf[nt],
                                                                acc[yt][nt], 0, 0, 0);
      }
    }
  }

  float bv[4];
#pragma unroll
  for (int nt = 0; nt < 4; ++nt) bv[nt] = b3[oh * 64 + nt * 16 + l15];
#pragma unroll
  for (int yt = 0; yt < 4; ++yt)
#pragma unroll
    for (int nt = 0; nt < 4; ++nt)
#pragma unroll
      for (int r = 0; r < 4; ++r) {
        int px = (wave * 4 + yt) * 16 + quad * 4 + r;
        h3[((size_t)pair * 256 + px) * 128 + oh * 64 + nt * 16 + l15] =
            fmaxf(acc[yt][nt][r] + bv[nt], 0.f);
      }
}

// ---------- kernel 7: conv4 1x1 (128->1) + loss + hardtanh + chamfer --------
__global__ __launch_bounds__(256) void k_conv4(const float* __restrict__ h3,
                                               const float* __restrict__ w4,
                                               const float* __restrict__ b4,
                                               float* __restrict__ out) {
  __shared__ float ws4[128];
  __shared__ float rowmax[16];
  __shared__ float lsum[4];
  const int pair = blockIdx.x, tid = threadIdx.x;
  if (tid < 128) ws4[tid] = w4[tid];
  __syncthreads();
  float h = b4[0];
  const float4* p = (const float4*)(h3 + ((size_t)pair * 256 + tid) * 128);
#pragma unroll 8
  for (int i = 0; i < 32; ++i) {
    float4 v = p[i];
    h += v.x * ws4[i * 4] + v.y * ws4[i * 4 + 1] + v.z * ws4[i * 4 + 2] +
         v.w * ws4[i * 4 + 3];
  }
  float loss = fmaxf(-(h + 1.f), 0.f) + fmaxf(h - 1.f, 0.f);
  float sc = fminf(fmaxf(h, -1.f), 1.f) * 0.5f + 0.5f;
#pragma unroll
  for (int off = 8; off >= 1; off >>= 1) sc = fmaxf(sc, __shfl_xor(sc, off, 16));
#pragma unroll
  for (int off = 32; off >= 1; off >>= 1) loss += __shfl_xor(loss, off, 64);
  if ((tid & 15) == 0) rowmax[tid >> 4] = sc;
  if ((tid & 63) == 0) lsum[tid >> 6] = loss;
  __syncthreads();
  if (tid == 0) {
    float mean = 0.f;
#pragma unroll
    for (int i = 0; i < 16; ++i) mean += rowmax[i];
    out[pair] = mean * (1.f / 16.f);
    atomicAdd(out + 64, lsum[0] + lsum[1] + lsum[2] + lsum[3]);
  }
}

extern "C" void kernel_launch(void* const* d_in, const int* in_sizes, int n_in,
                              void* d_out, int out_size, void* d_ws, size_t ws_size,
                              hipStream_t stream) {
  (void)in_sizes; (void)n_in; (void)out_size; (void)ws_size;
  const float* x  = (const float*)d_in[0];
  const float* w1 = (const float*)d_in[1];
  const float* b1 = (const float*)d_in[2];
  const float* w2 = (const float*)d_in[3];
  const float* b2 = (const float*)d_in[4];
  const float* w3 = (const float*)d_in[5];
  const float* b3 = (const float*)d_in[6];
  const float* w4 = (const float*)d_in[7];
  const float* b4 = (const float*)d_in[8];
  float* out = (float*)d_out;

  char* ws = (char*)d_ws;
  u16*   Abf  = (u16*)ws;                   // 4,718,592 B
  float* Smax = (float*)(ws + 4718592);     // 9,437,184 B  [4608][512]
  float* Sx   = (float*)(ws + 14155776);    //   663,552 B  [4608][36]
  float* sim  = (float*)(ws + 14819328);    // 1,048,576 B
  u16*   h1   = (u16*)(ws + 15867904);      // 4,194,304 B  (bf16 chan-last)
  u16*   h2   = (u16*)(ws + 20062208);      // 2,097,152 B  (bf16 chan-last)
  float* h3   = (float*)(ws + 22159360);    // 8,388,608 B  (fp32 chan-last)
  u16*   wp2  = (u16*)(ws + 30547968);      //    36,864 B
  u16*   wp3  = (u16*)(ws + 30584832);      //   147,456 B  (end ~30.7 MB)

  k_cast<<<1152, 256, 0, stream>>>(x, Abf, w2, w3, wp2, wp3, out);
  k_gemm_smax<<<666, 256, 0, stream>>>(Abf, Smax, Sx);
  k_reduce_o<<<1024, 256, 0, stream>>>(Smax, Sx, sim);
  k_conv1pool<<<dim3(64, 4), 256, 0, stream>>>(sim, w1, b1, h1);
  k_conv2pool<<<dim3(64, 2), 256, 0, stream>>>(h1, wp2, b2, h2);
  k_conv3<<<dim3(64, 2), 256, 0, stream>>>(h2, wp3, b3, h3);
  k_conv4<<<64, 256, 0, stream>>>(h3, w4, b4, out);
}

// Round 13
// 159.223 us; speedup vs baseline: 1.0215x; 1.0215x over previous
//
#include <hip/hip_runtime.h>

typedef unsigned short u16;
typedef unsigned int u32;
typedef __bf16 bf16x8 __attribute__((ext_vector_type(8)));
typedef u16 u16x8 __attribute__((ext_vector_type(8)));
typedef float f32x4 __attribute__((ext_vector_type(4)));

__device__ __forceinline__ u16 f2bf(float f) {
  u32 u = __float_as_uint(f);
  u32 r = (u + 0x7FFFu + ((u >> 16) & 1u)) >> 16;  // RNE
  return (u16)r;
}

// async global->LDS, 16B per lane: LDS dest = wave-uniform base + lane*16
__device__ __forceinline__ void gload16(const void* g, void* l) {
  typedef __attribute__((address_space(1))) const void gvoid;
  typedef __attribute__((address_space(3))) void lvoid;
  __builtin_amdgcn_global_load_lds((gvoid*)g, (lvoid*)l, 16, 0, 0);
}

// -------- kernel 0: cast x fp32 -> bf16 A[4608][512]  (+ wpack + out-zero) --
__global__ void k_cast(const float* __restrict__ x, u16* __restrict__ A,
                       const float* __restrict__ w2, const float* __restrict__ w3,
                       u16* __restrict__ p2, u16* __restrict__ p3,
                       float* __restrict__ out) {
  int t = blockIdx.x * 256 + threadIdx.x;
  const float4* xp = (const float4*)x + (size_t)t * 2;
  float4 v0 = xp[0], v1 = xp[1];
  u16x8 r;
  r[0] = f2bf(v0.x); r[1] = f2bf(v0.y); r[2] = f2bf(v0.z); r[3] = f2bf(v0.w);
  r[4] = f2bf(v1.x); r[5] = f2bf(v1.y); r[6] = f2bf(v1.z); r[7] = f2bf(v1.w);
  *(u16x8*)(A + (size_t)t * 8) = r;
  if (blockIdx.x == 0 && threadIdx.x < 65) out[threadIdx.x] = 0.f;
  if (t < 18432) {
    int tt = t >> 11, oc = (t >> 5) & 63, ic = t & 31;
    p2[t] = f2bf(w2[(oc * 32 + ic) * 9 + tt]);
  }
  if (t < 73728) {
    int tt = t >> 13, oc = (t >> 6) & 127, ic = t & 63;
    p3[t] = f2bf(w3[(oc * 64 + ic) * 9 + tt]);
  }
}

// ------- kernel 1: symmetric C = A*A^T with fused max over col/row 9-groups -
// K-loop: R10 DMA-dbuf (best measured). R13: XCD-locality remap — the 666
// triangle tiles are split into 8 contiguous chunks; blockIdx = i*8 + chunk
// so the round-robin dispatch pins each chunk to one XCD: the 128KB row-slab
// is then reused ~30x from that XCD's L2 instead of re-fetched from L3/HBM
// (R12: FETCH 27MB = 5.7x |A|, MfmaUtil 9%, latency-bound).
__global__ __launch_bounds__(256) void k_gemm_smax(const u16* __restrict__ A,
                                                   float* __restrict__ Smax,
                                                   float* __restrict__ Sx) {
  __shared__ char smem[65536];   // 2 x (As 16KB + Bs 16KB); epilogue slab reuses
  float* slab = (float*)smem;    // 64 x 129 f32 = 33024 B, used after K-loop
  // chunk decode: sizes [84,84,83,83,83,83,83,83], grid = 672 (6 dummies)
  const int chunk = blockIdx.x & 7, ci = blockIdx.x >> 3;
  const int csz = (chunk < 2) ? 84 : 83;
  if (ci >= csz) return;
  const int tlin = ((chunk < 2) ? 84 * chunk : 168 + 83 * (chunk - 2)) + ci;
  int rb = (int)((73.0f - sqrtf((float)(5329 - 8 * tlin))) * 0.5f);
  while (rb * 36 - rb * (rb - 1) / 2 > tlin) --rb;                  // safety
  while ((rb + 1) * 36 - (rb + 1) * rb / 2 <= tlin) ++rb;           // safety
  const int cb = rb + (tlin - (rb * 36 - rb * (rb - 1) / 2));
  const int rowBase = rb * 128, colBase = cb * 128;
  const int tid = threadIdx.x, wave = tid >> 6, lane = tid & 63;
  const int lr = lane >> 3, lc = lane & 7;     // staging: 8 rows x 8 chunks
  const int lrow = lane & 15, lk = lane >> 4;  // mfma fragment map
  const int xr = lrow & 7;
  const int wr = (wave & 1) * 64, wc = (wave >> 1) * 64;

  f32x4 acc[4][4];
#pragma unroll
  for (int rt = 0; rt < 4; ++rt)
#pragma unroll
    for (int ct = 0; ct < 4; ++ct) { f32x4 z = {0.f, 0.f, 0.f, 0.f}; acc[rt][ct] = z; }

  // prologue: stage k0=0 into buffer 0
  {
    u16* As = (u16*)smem;
    u16* Bs = (u16*)(smem + 16384);
#pragma unroll
    for (int ii = 0; ii < 4; ++ii) {
      int r0 = wave * 32 + ii * 8;
      gload16(A + (size_t)(rowBase + r0 + lr) * 512 + ((lc ^ lr) * 8), As + r0 * 64);
      gload16(A + (size_t)(colBase + r0 + lr) * 512 + ((lc ^ lr) * 8), Bs + r0 * 64);
    }
  }
  __syncthreads();
  for (int k = 0; k < 8; ++k) {
    if (k < 7) {  // prefetch next tile into the other buffer
      char* base = smem + (((k + 1) & 1) << 15);
      u16* As = (u16*)base;
      u16* Bs = (u16*)(base + 16384);
      int k0 = (k + 1) * 64;
#pragma unroll
      for (int ii = 0; ii < 4; ++ii) {
        int r0 = wave * 32 + ii * 8;
        gload16(A + (size_t)(rowBase + r0 + lr) * 512 + k0 + ((lc ^ lr) * 8),
                As + r0 * 64);
        gload16(A + (size_t)(colBase + r0 + lr) * 512 + k0 + ((lc ^ lr) * 8),
                Bs + r0 * 64);
      }
    }
    {
      char* base = smem + ((k & 1) << 15);
      u16* As = (u16*)base;
      u16* Bs = (u16*)(base + 16384);
#pragma unroll
      for (int s = 0; s < 2; ++s) {
        bf16x8 af[4], bf[4];
#pragma unroll
        for (int rt = 0; rt < 4; ++rt)
          af[rt] = *(const bf16x8*)(As + (wr + rt * 16 + lrow) * 64 +
                                    ((u32)(s * 4 + lk) ^ xr) * 8);
#pragma unroll
        for (int ct = 0; ct < 4; ++ct)
          bf[ct] = *(const bf16x8*)(Bs + (wc + ct * 16 + lrow) * 64 +
                                    ((u32)(s * 4 + lk) ^ xr) * 8);
#pragma unroll
        for (int rt = 0; rt < 4; ++rt)
#pragma unroll
          for (int ct = 0; ct < 4; ++ct)
            acc[rt][ct] = __builtin_amdgcn_mfma_f32_16x16x32_bf16(af[rt], bf[ct],
                                                                  acc[rt][ct], 0, 0, 0);
      }
    }
    __syncthreads();
  }

  // C/D layout: col=lane&15, row=(lane>>4)*4+reg [measured]. Verified R8-R12.
  const int g0c = colBase / 9, offc = colBase % 9;
  const int g0r = rowBase / 9, offr = rowBase % 9;
  const int nph = (rb == cb) ? 2 : 4;
  for (int ph = 0; ph < nph; ++ph) {
    __syncthreads();
    if (ph < 2) {
      if ((wave & 1) == ph) {
#pragma unroll
        for (int rt = 0; rt < 4; ++rt)
#pragma unroll
          for (int ct = 0; ct < 4; ++ct)
#pragma unroll
            for (int r = 0; r < 4; ++r)
              slab[(rt * 16 + lk * 4 + r) * 129 + wc + ct * 16 + lrow] = acc[rt][ct][r];
      }
    } else {
      if ((wave >> 1) == ph - 2) {
#pragma unroll
        for (int rt = 0; rt < 4; ++rt)
#pragma unroll
          for (int ct = 0; ct < 4; ++ct)
#pragma unroll
            for (int r = 0; r < 4; ++r)
              slab[(ct * 16 + lrow) * 129 + wr + rt * 16 + lk * 4 + r] = acc[rt][ct][r];
      }
    }
    __syncthreads();
    for (int it = tid; it < 1024; it += 256) {
      int line = it >> 4, s = it & 15;
      float m = -3.0e38f;
      if (ph < 2) {
        int g = g0c + s;
        int cs = 9 * g - colBase, ce = cs + 9;
        cs = cs < 0 ? 0 : cs;
        ce = ce > 128 ? 128 : ce;
        if (cs >= ce) continue;
        const float* p = slab + line * 129;
        for (int c = cs; c < ce; ++c) m = fmaxf(m, p[c]);
        int r = rowBase + ph * 64 + line;
        if (s == 0 && offc != 0) Sx[(size_t)r * 36 + (cb - 1)] = m;
        else Smax[(size_t)r * 512 + g] = m;
      } else {
        int g = g0r + s;
        int rs = 9 * g - rowBase, re = rs + 9;
        rs = rs < 0 ? 0 : rs;
        re = re > 128 ? 128 : re;
        if (rs >= re) continue;
        const float* p = slab + line * 129;
        for (int r2 = rs; r2 < re; ++r2) m = fmaxf(m, p[r2]);
        int cgl = colBase + (ph - 2) * 64 + line;
        if (s == 0 && offr != 0) Sx[(size_t)cgl * 36 + (rb - 1)] = m;
        else Smax[(size_t)cgl * 512 + g] = m;
      }
    }
  }
}

// ---------- kernel 2: mean over o (+Sx boundary combine) -> sim -------------
__global__ void k_reduce_o(const float* __restrict__ Smax, const float* __restrict__ Sx,
                           float* __restrict__ sim) {
  int idx = blockIdx.x * 256 + threadIdx.x;  // 262144
  int j = idx & 63, i = (idx >> 6) & 63, b = (idx >> 12) & 7, a = idx >> 15;
  int g = b * 64 + j;
  int t9 = 9 * g;
  int k = (t9 + 8) >> 7;                        // candidate tile boundary
  bool part = ((u32)(128 * k - t9 - 1) < 8u);   // 128k strictly inside (t9, t9+9)
  const float* p = Smax + (size_t)(a * 576 + i * 9) * 512 + g;
  const float* q = Sx + (size_t)(a * 576 + i * 9) * 36 + (k - 1);
  float s = 0.f;
#pragma unroll
  for (int o = 0; o < 9; ++o) {
    float v = p[o * 512];
    if (part) v = fmaxf(v, q[o * 36]);
    s += v;
  }
  sim[idx] = s * (1.f / 9.f);  // sim[(a*8+b)*4096 + i*64 + j]
}

// ---------- kernel 3: conv1 (1->32) + ReLU + maxpool2, channels-last bf16 ---
__global__ __launch_bounds__(256) void k_conv1pool(const float* __restrict__ sim,
                                                   const float* __restrict__ w1,
                                                   const float* __restrict__ b1,
                                                   u16* __restrict__ h1) {
  __shared__ float tin[4096];
  const int pair = blockIdx.x, ocg = blockIdx.y, tid = threadIdx.x;
  const float4* src = (const float4*)(sim + (size_t)pair * 4096);
  for (int i = tid; i < 1024; i += 256) ((float4*)tin)[i] = src[i];
  __syncthreads();
  float wv[8][9], bs[8];
#pragma unroll
  for (int o = 0; o < 8; ++o) {
#pragma unroll
    for (int q = 0; q < 9; ++q) wv[o][q] = w1[(ocg * 8 + o) * 9 + q];
    bs[o] = b1[ocg * 8 + o];
  }
  for (int pp = tid; pp < 1024; pp += 256) {
    int py = pp >> 5, px = pp & 31;
    float m[8];
#pragma unroll
    for (int o = 0; o < 8; ++o) m[o] = 0.f;
#pragma unroll
    for (int dy = 0; dy < 2; ++dy)
#pragma unroll
      for (int dx = 0; dx < 2; ++dx) {
        float s[8];
#pragma unroll
        for (int o = 0; o < 8; ++o) s[o] = bs[o];
        int yy = py * 2 + dy, xx0 = px * 2 + dx;
#pragma unroll
        for (int ky = 0; ky < 3; ++ky) {
          int y = yy + ky - 1;
          if ((unsigned)y < 64u) {
#pragma unroll
            for (int kx = 0; kx < 3; ++kx) {
              int x = xx0 + kx - 1;
              if ((unsigned)x < 64u) {
                float v = tin[y * 64 + x];
#pragma unroll
                for (int o = 0; o < 8; ++o) s[o] += wv[o][ky * 3 + kx] * v;
              }
            }
          }
        }
#pragma unroll
        for (int o = 0; o < 8; ++o) m[o] = fmaxf(m[o], fmaxf(s[o], 0.f));
      }
    u16x8 r;
#pragma unroll
    for (int o = 0; o < 8; ++o) r[o] = f2bf(m[o]);
    *(u16x8*)&h1[(((size_t)pair * 32 + py) * 32 + px) * 32 + ocg * 8] = r;
  }
}

// ---------- kernel 4: conv2 MFMA (32->64) + ReLU + maxpool2 -----------------
__global__ __launch_bounds__(256) void k_conv2pool(const u16* __restrict__ h1,
                                                   const u16* __restrict__ wp2,
                                                   const float* __restrict__ b2,
                                                   u16* __restrict__ h2) {
  __shared__ u16 tile[18 * 34 * 40];  // 48960 B
  const int pair = blockIdx.x, yh = blockIdx.y, tid = threadIdx.x;
  const int wave = tid >> 6, lane = tid & 63, l15 = lane & 15, quad = lane >> 4;
  u16x8 z8 = {0, 0, 0, 0, 0, 0, 0, 0};
  for (int i = tid; i < 3060; i += 256) ((u16x8*)tile)[i] = z8;
  __syncthreads();
  for (int f = tid; f < 1152; f += 256) {
    int i = f >> 6, rem = f & 63, px = rem >> 1, half = rem & 1;
    int gr = yh * 16 - 1 + i;
    if ((unsigned)gr < 32u)
      *(u16x8*)&tile[(i * 34 + 1 + px) * 40 + half * 16] =
          *(const u16x8*)&h1[(((size_t)pair * 32 + gr) * 32 + px) * 32 + half * 16];
  }
  __syncthreads();

  f32x4 acc[8][4];
#pragma unroll
  for (int m = 0; m < 8; ++m)
#pragma unroll
    for (int n = 0; n < 4; ++n) { f32x4 z = {0.f, 0.f, 0.f, 0.f}; acc[m][n] = z; }

  for (int t = 0; t < 9; ++t) {
    int ky = t / 3, kx = t % 3;
    bf16x8 wf[4];
#pragma unroll
    for (int nt = 0; nt < 4; ++nt)
      wf[nt] = *(const bf16x8*)&wp2[((t * 64 + nt * 16 + l15) << 5) + quad * 8];
#pragma unroll
    for (int rr = 0; rr < 4; ++rr)
#pragma unroll
      for (int xh = 0; xh < 2; ++xh) {
        int lr = wave * 4 + rr;
        bf16x8 af = *(const bf16x8*)&tile[((lr + ky) * 34 + xh * 16 + l15 + kx) * 40 +
                                          quad * 8];
#pragma unroll
        for (int nt = 0; nt < 4; ++nt)
          acc[rr * 2 + xh][nt] =
              __builtin_amdgcn_mfma_f32_16x16x32_bf16(af, wf[nt], acc[rr * 2 + xh][nt],
                                                      0, 0, 0);
      }
  }

  float bv[4];
#pragma unroll
  for (int nt = 0; nt < 4; ++nt) bv[nt] = b2[nt * 16 + l15];
#pragma unroll
  for (int rp = 0; rp < 2; ++rp)
#pragma unroll
    for (int xh = 0; xh < 2; ++xh) {
      int py = yh * 8 + wave * 2 + rp;
      int px0 = xh * 8 + quad * 2;
#pragma unroll
      for (int nt = 0; nt < 4; ++nt) {
        f32x4 va = acc[(rp * 2) * 2 + xh][nt], vb = acc[(rp * 2 + 1) * 2 + xh][nt];
        float p0 = fmaxf(fmaxf(fmaxf(va[0], va[1]), fmaxf(vb[0], vb[1])) + bv[nt], 0.f);
        float p1 = fmaxf(fmaxf(fmaxf(va[2], va[3]), fmaxf(vb[2], vb[3])) + bv[nt], 0.f);
        size_t base = (((size_t)pair * 16 + py) * 16 + px0) * 64 + nt * 16 + l15;
        h2[base] = f2bf(p0);
        h2[base + 64] = f2bf(p1);
      }
    }
}

// ---------- kernel 5: conv3 MFMA (64->128) + ReLU ---------------------------
__global__ __launch_bounds__(256) void k_conv3(const u16* __restrict__ h2,
                                               const u16* __restrict__ wp3,
                                               const float* __restrict__ b3,
                                               float* __restrict__ h3) {
  __shared__ u16 tile[18 * 18 * 72];  // 46656 B
  const int pair = blockIdx.x, oh = blockIdx.y, tid = threadIdx.x;
  const int wave = tid >> 6, lane = tid & 63, l15 = lane & 15, quad = lane >> 4;
  u16x8 z8 = {0, 0, 0, 0, 0, 0, 0, 0};
  for (int i = tid; i < 2916; i += 256) ((u16x8*)tile)[i] = z8;
  __syncthreads();
  for (int f = tid; f < 2048; f += 256) {
    int row = f >> 7, rem = f & 127, px = rem >> 3, seg = rem & 7;
    *(u16x8*)&tile[((row + 1) * 18 + px + 1) * 72 + seg * 8] =
        *(const u16x8*)&h2[(((size_t)pair * 16 + row) * 16 + px) * 64 + seg * 8];
  }
  __syncthreads();

  f32x4 acc[4][4];
#pragma unroll
  for (int m = 0; m < 4; ++m)
#pragma unroll
    for (int n = 0; n < 4; ++n) { f32x4 z = {0.f, 0.f, 0.f, 0.f}; acc[m][n] = z; }

  for (int t = 0; t < 9; ++t) {
    int ky = t / 3, kx = t % 3;
#pragma unroll
    for (int s = 0; s < 2; ++s) {
      bf16x8 wf[4];
#pragma unroll
      for (int nt = 0; nt < 4; ++nt)
        wf[nt] = *(const bf16x8*)&wp3[((t * 128 + oh * 64 + nt * 16 + l15) << 6) +
                                      s * 32 + quad * 8];
#pragma unroll
      for (int yt = 0; yt < 4; ++yt) {
        int y = wave * 4 + yt;
        bf16x8 af = *(const bf16x8*)&tile[((y + ky) * 18 + l15 + kx) * 72 + s * 32 +
                                          quad * 8];
#pragma unroll
        for (int nt = 0; nt < 4; ++nt)
          acc[yt][nt] = __builtin_amdgcn_mfma_f32_16x16x32_bf16(af, wf[nt],
                                                                acc[yt][nt], 0, 0, 0);
      }
    }
  }

  float bv[4];
#pragma unroll
  for (int nt = 0; nt < 4; ++nt) bv[nt] = b3[oh * 64 + nt * 16 + l15];
#pragma unroll
  for (int yt = 0; yt < 4; ++yt)
#pragma unroll
    for (int nt = 0; nt < 4; ++nt)
#pragma unroll
      for (int r = 0; r < 4; ++r) {
        int px = (wave * 4 + yt) * 16 + quad * 4 + r;
        h3[((size_t)pair * 256 + px) * 128 + oh * 64 + nt * 16 + l15] =
            fmaxf(acc[yt][nt][r] + bv[nt], 0.f);
      }
}

// ---------- kernel 7: conv4 1x1 (128->1) + loss + hardtanh + chamfer --------
__global__ __launch_bounds__(256) void k_conv4(const float* __restrict__ h3,
                                               const float* __restrict__ w4,
                                               const float* __restrict__ b4,
                                               float* __restrict__ out) {
  __shared__ float ws4[128];
  __shared__ float rowmax[16];
  __shared__ float lsum[4];
  const int pair = blockIdx.x, tid = threadIdx.x;
  if (tid < 128) ws4[tid] = w4[tid];
  __syncthreads();
  float h = b4[0];
  const float4* p = (const float4*)(h3 + ((size_t)pair * 256 + tid) * 128);
#pragma unroll 8
  for (int i = 0; i < 32; ++i) {
    float4 v = p[i];
    h += v.x * ws4[i * 4] + v.y * ws4[i * 4 + 1] + v.z * ws4[i * 4 + 2] +
         v.w * ws4[i * 4 + 3];
  }
  float loss = fmaxf(-(h + 1.f), 0.f) + fmaxf(h - 1.f, 0.f);
  float sc = fminf(fmaxf(h, -1.f), 1.f) * 0.5f + 0.5f;
#pragma unroll
  for (int off = 8; off >= 1; off >>= 1) sc = fmaxf(sc, __shfl_xor(sc, off, 16));
#pragma unroll
  for (int off = 32; off >= 1; off >>= 1) loss += __shfl_xor(loss, off, 64);
  if ((tid & 15) == 0) rowmax[tid >> 4] = sc;
  if ((tid & 63) == 0) lsum[tid >> 6] = loss;
  __syncthreads();
  if (tid == 0) {
    float mean = 0.f;
#pragma unroll
    for (int i = 0; i < 16; ++i) mean += rowmax[i];
    out[pair] = mean * (1.f / 16.f);
    atomicAdd(out + 64, lsum[0] + lsum[1] + lsum[2] + lsum[3]);
  }
}

extern "C" void kernel_launch(void* const* d_in, const int* in_sizes, int n_in,
                              void* d_out, int out_size, void* d_ws, size_t ws_size,
                              hipStream_t stream) {
  (void)in_sizes; (void)n_in; (void)out_size; (void)ws_size;
  const float* x  = (const float*)d_in[0];
  const float* w1 = (const float*)d_in[1];
  const float* b1 = (const float*)d_in[2];
  const float* w2 = (const float*)d_in[3];
  const float* b2 = (const float*)d_in[4];
  const float* w3 = (const float*)d_in[5];
  const float* b3 = (const float*)d_in[6];
  const float* w4 = (const float*)d_in[7];
  const float* b4 = (const float*)d_in[8];
  float* out = (float*)d_out;

  char* ws = (char*)d_ws;
  u16*   Abf  = (u16*)ws;                   // 4,718,592 B
  float* Smax = (float*)(ws + 4718592);     // 9,437,184 B  [4608][512]
  float* Sx   = (float*)(ws + 14155776);    //   663,552 B  [4608][36]
  float* sim  = (float*)(ws + 14819328);    // 1,048,576 B
  u16*   h1   = (u16*)(ws + 15867904);      // 4,194,304 B  (bf16 chan-last)
  u16*   h2   = (u16*)(ws + 20062208);      // 2,097,152 B  (bf16 chan-last)
  float* h3   = (float*)(ws + 22159360);    // 8,388,608 B  (fp32 chan-last)
  u16*   wp2  = (u16*)(ws + 30547968);      //    36,864 B
  u16*   wp3  = (u16*)(ws + 30584832);      //   147,456 B  (end ~30.7 MB)

  k_cast<<<1152, 256, 0, stream>>>(x, Abf, w2, w3, wp2, wp3, out);
  k_gemm_smax<<<672, 256, 0, stream>>>(Abf, Smax, Sx);
  k_reduce_o<<<1024, 256, 0, stream>>>(Smax, Sx, sim);
  k_conv1pool<<<dim3(64, 4), 256, 0, stream>>>(sim, w1, b1, h1);
  k_conv2pool<<<dim3(64, 2), 256, 0, stream>>>(h1, wp2, b2, h2);
  k_conv3<<<dim3(64, 2), 256, 0, stream>>>(h2, wp3, b3, h3);
  k_conv4<<<64, 256, 0, stream>>>(h3, w4, b4, out);
}